// Round 14
// baseline (1298.997 us; speedup 1.0000x reference)
//
#include <hip/hip_runtime.h>

#define B_ 8192
#define D_ 1024
#define K_ 4096
#define H_ 8

#define BM 128   // resid rows per block
#define BN 128   // codebook rows per block
#define NBLK 64        // 64-codeword argmin blocks per row
#define TOPB 3         // candidates kept per block
#define NCAND 8        // exact-rescored candidates per row

typedef __attribute__((ext_vector_type(4))) float f32x4;

#define FINF 3.4e38f
#define IBIG 0x7fffffff

__device__ __forceinline__ void amin(float& v, int& i, float v2, int i2) {
    if (v2 < v || (v2 == v && i2 < i)) { v = v2; i = i2; }
}

// fp32 -> OCP e4m3fn (RNE, saturate 448, flush |x|<2^-6 -> 0; approx-only path)
__device__ __forceinline__ unsigned char f2e4m3(float x) {
    unsigned int u = __float_as_uint(x);
    unsigned int s = (u >> 24) & 0x80u;
    unsigned int au = u & 0x7fffffffu;
    float ax = __uint_as_float(au);
    if (ax < 0.015625f) return (unsigned char)s;
    if (ax > 448.f) return (unsigned char)(s | 0x7E);
    au = au + 0x7FFFFu + ((au >> 20) & 1u);      // RNE to 3 mantissa bits
    int e8 = (int)(au >> 23) - 120;              // rebias 127 -> 7
    unsigned int m3 = (au >> 20) & 7u;
    if (e8 >= 16) return (unsigned char)(s | 0x7E);
    if (e8 < 1) return (unsigned char)s;
    return (unsigned char)(s | ((unsigned)e8 << 3) | m3);
}

__device__ __forceinline__ void gload16(const void* g, void* l) {
    __builtin_amdgcn_global_load_lds(
        (const __attribute__((address_space(1))) void*)g,
        (__attribute__((address_space(3))) void*)l, 16, 0, 0);
}

// ---------------------------------------------------------------------------
// Per head: codebook row -> fp8(E * 2^h) + ee[k] = ||E_k||^2 (exact fp32)
// ---------------------------------------------------------------------------
__global__ __launch_bounds__(256) void cbconv_kernel(const float* __restrict__ E,
                                                     unsigned char* __restrict__ c8,
                                                     float* __restrict__ eeh,
                                                     float scale) {
    const int row = blockIdx.x;
    const int t = threadIdx.x;
    float4 v = reinterpret_cast<const float4*>(E + (size_t)row * D_)[t];
    uchar4 q;
    q.x = f2e4m3(v.x * scale); q.y = f2e4m3(v.y * scale);
    q.z = f2e4m3(v.z * scale); q.w = f2e4m3(v.w * scale);
    reinterpret_cast<uchar4*>(c8 + (size_t)row * D_)[t] = q;
    float s = v.x * v.x + v.y * v.y + v.z * v.z + v.w * v.w;
    #pragma unroll
    for (int m = 1; m < 64; m <<= 1) s += __shfl_xor(s, m);
    __shared__ float ls[4];
    if ((t & 63) == 0) ls[t >> 6] = s;
    __syncthreads();
    if (t == 0) eeh[row] = (ls[0] + ls[1]) + (ls[2] + ls[3]);
}

// ---------------------------------------------------------------------------
// resid = x ; rr = ||x||^2 ; resid fp8
// ---------------------------------------------------------------------------
__global__ __launch_bounds__(256) void init_kernel(const float* __restrict__ x,
                                                   float* __restrict__ resid,
                                                   float* __restrict__ rr,
                                                   unsigned char* __restrict__ r8) {
    const int b = blockIdx.x;
    const int t = threadIdx.x;
    float4 v = reinterpret_cast<const float4*>(x + (size_t)b * D_)[t];
    reinterpret_cast<float4*>(resid + (size_t)b * D_)[t] = v;
    uchar4 q;
    q.x = f2e4m3(v.x); q.y = f2e4m3(v.y);
    q.z = f2e4m3(v.z); q.w = f2e4m3(v.w);
    reinterpret_cast<uchar4*>(r8 + (size_t)b * D_)[t] = q;
    float s = v.x * v.x + v.y * v.y + v.z * v.z + v.w * v.w;
    #pragma unroll
    for (int m = 1; m < 64; m <<= 1) s += __shfl_xor(s, m);
    __shared__ float ls[4];
    if ((t & 63) == 0) ls[t >> 6] = s;
    __syncthreads();
    if (t == 0) rr[b] = (ls[0] + ls[1]) + (ls[2] + ls[3]);
}

// ---------------------------------------------------------------------------
// fp8 swapped-operand MFMA approx score + lane-local TOP-3 argmin.
//   A = fp8(codebook * 2^h), B = fp8(resid); mfma_f32_16x16x32_fp8_fp8.
//   C layout: E-row = i*16 + (l>>4)*4 + reg ; resid col = j*16 + (l&15).
// Rank value = 2^h*ee[k] - 2*dot8 (positive scale => rank-preserving).
// Staging halves vs bf16: 8 KB/iter, ds_read_b64 fragments.
// XCD-aware decode kept from round 12.
// ---------------------------------------------------------------------------
__global__ __launch_bounds__(256) void score_mfma_kernel(
    const unsigned char* __restrict__ C8,   // fp8 codebook [K][D]
    const unsigned char* __restrict__ R8,   // fp8 resid [B][D]
    const float* __restrict__ ee, float sH,
    float* __restrict__ pval, int* __restrict__ pidx) {
    __shared__ __align__(16) unsigned char lds8[2][128][32];   // 8 KB

    const int tid = threadIdx.x;
    const int bid = blockIdx.x;
    const int xcd = bid & 7;
    const int r_  = bid >> 3;
    const int bx  = (xcd << 2) | (r_ & 3);   // codebook tile 0..31
    const int by  = r_ >> 2;                 // resid tile 0..63
    const int be0 = bx * BN;
    const int br0 = by * BM;

    f32x4 acc[4][4];
    #pragma unroll
    for (int i = 0; i < 4; ++i)
        #pragma unroll
        for (int j = 0; j < 4; ++j)
            #pragma unroll
            for (int r = 0; r < 4; ++r) acc[i][j][r] = 0.f;

    // staging: thread t covers LDS bytes [t*16, t*16+16) of each 128x32 tile
    const int srow  = tid >> 1;
    const int sbyte = (tid & 1) * 16;
    const unsigned char* pC = C8 + (size_t)(be0 + srow) * D_ + sbyte;
    const unsigned char* pR = R8 + (size_t)(br0 + srow) * D_ + sbyte;

    const int l  = tid & 63;
    const int w  = tid >> 6;
    const int wr = (w >> 1) * 64;    // wave E offset
    const int wc = (w & 1) * 64;     // wave resid offset
    const int fr = l & 15;
    const int k8 = (l >> 4) * 8;     // byte offset of this lane's 8 k-elems

    for (int d0 = 0; d0 < D_; d0 += 32) {
        __syncthreads();
        gload16(pC + d0, &lds8[0][srow][sbyte]);
        gload16(pR + d0, &lds8[1][srow][sbyte]);
        __syncthreads();

        long a_l[4], b_l[4];
        #pragma unroll
        for (int f = 0; f < 4; ++f) {
            a_l[f] = *reinterpret_cast<const long*>(&lds8[0][wr + f * 16 + fr][k8]);
            b_l[f] = *reinterpret_cast<const long*>(&lds8[1][wc + f * 16 + fr][k8]);
        }
        #pragma unroll
        for (int i = 0; i < 4; ++i)
            #pragma unroll
            for (int j = 0; j < 4; ++j)
                acc[i][j] = __builtin_amdgcn_mfma_f32_16x16x32_fp8_fp8(a_l[i], b_l[j], acc[i][j], 0, 0, 0);
    }

    // ---- epilogue: per-resid-row top-3 over this wave's 64 E-rows ----
    const int g4 = (l >> 4) * 4;
    float ev[4][4];
    int ecd[4][4];
    #pragma unroll
    for (int i = 0; i < 4; ++i)
        #pragma unroll
        for (int r = 0; r < 4; ++r) {
            ecd[i][r] = be0 + wr + i * 16 + g4 + r;
            ev[i][r] = ee[ecd[i][r]] * sH;
        }
    const int eblk = bx * 2 + (w >> 1);   // 64-E-row block id 0..63

    #define INS3(v, c) do {                                         \
        const float _v = (v); const int _c = (c);                   \
        if (_v < b1 || (_v == b1 && _c < i1)) {                     \
            b3 = b2; i3 = i2; b2 = b1; i2 = i1; b1 = _v; i1 = _c;   \
        } else if (_v < b2 || (_v == b2 && _c < i2)) {              \
            b3 = b2; i3 = i2; b2 = _v; i2 = _c;                     \
        } else if (_v < b3 || (_v == b3 && _c < i3)) {              \
            b3 = _v; i3 = _c;                                       \
        }                                                           \
    } while (0)

    #pragma unroll
    for (int j = 0; j < 4; ++j) {
        const int rrow = br0 + wc + j * 16 + fr;
        float b1 = FINF, b2 = FINF, b3 = FINF;
        int i1 = IBIG, i2 = IBIG, i3 = IBIG;
        #pragma unroll
        for (int i = 0; i < 4; ++i)
            #pragma unroll
            for (int r = 0; r < 4; ++r) {
                const float s = fmaf(-2.0f, acc[i][j][r], ev[i][r]);
                INS3(s, ecd[i][r]);
            }
        #pragma unroll
        for (int m = 16; m < 64; m <<= 1) {
            const float o1 = __shfl_xor(b1, m); const int oi1 = __shfl_xor(i1, m);
            const float o2 = __shfl_xor(b2, m); const int oi2 = __shfl_xor(i2, m);
            const float o3 = __shfl_xor(b3, m); const int oi3 = __shfl_xor(i3, m);
            INS3(o1, oi1); INS3(o2, oi2); INS3(o3, oi3);
        }
        if ((l >> 4) == 0) {
            const size_t base = ((size_t)rrow * NBLK + eblk) * TOPB;
            pval[base] = b1;     pidx[base] = i1;
            pval[base + 1] = b2; pidx[base + 1] = i2;
            pval[base + 2] = b3; pidx[base + 2] = i3;
        }
    }
    #undef INS3
}

// ---------------------------------------------------------------------------
// Wave-per-row update: 4 rows per block, no LDS. Top-NCAND extraction from
// 192 partials, EXACT fp32 rescore, argmin (value then lowest index), exact
// resid update + fp8 re-encode. Last head emits quantized = x - resid_new.
// ---------------------------------------------------------------------------
__global__ __launch_bounds__(256) void update_kernel(
    float* __restrict__ resid,
    const float* __restrict__ E,
    const float* __restrict__ ee,
    const float* __restrict__ pval,
    const int* __restrict__ pidx,
    float* __restrict__ rr,
    float* __restrict__ codes,
    unsigned char* __restrict__ r8,
    const float* __restrict__ x,
    float* __restrict__ quant,
    int h) {
    const int w = threadIdx.x >> 6;
    const int l = threadIdx.x & 63;
    const int b = blockIdx.x * 4 + w;

    // --- candidate extraction: lane l owns the 3 partials of block l
    const size_t pbase = ((size_t)b * NBLK + l) * TOPB;
    float v0 = pval[pbase], v1 = pval[pbase + 1], v2 = pval[pbase + 2];
    int i0 = pidx[pbase], i1 = pidx[pbase + 1], i2 = pidx[pbase + 2];
    int cand[NCAND];
    #pragma unroll
    for (int r = 0; r < NCAND; ++r) {
        float av = v0; int ai = i0;
        amin(av, ai, v1, i1);
        amin(av, ai, v2, i2);
        #pragma unroll
        for (int m = 1; m < 64; m <<= 1) {
            float ov = __shfl_xor(av, m);
            int oi = __shfl_xor(ai, m);
            amin(av, ai, ov, oi);
        }
        if (ai == i0) v0 = FINF;   // consume (indices unique across partials)
        if (ai == i1) v1 = FINF;
        if (ai == i2) v2 = FINF;
        cand[r] = ai;              // uniform across the wave
    }

    // --- resid row into registers (reused for rescore AND update)
    const float4* r4row = reinterpret_cast<const float4*>(resid + (size_t)b * D_);
    float4 rx[4];
    #pragma unroll
    for (int q = 0; q < 4; ++q) rx[q] = r4row[q * 64 + l];

    // --- exact fp32 rescore of the NCAND candidates
    float dots[NCAND];
    #pragma unroll
    for (int c = 0; c < NCAND; ++c) {
        const float4* e4 = reinterpret_cast<const float4*>(E + (size_t)cand[c] * D_);
        float dot = 0.f;
        #pragma unroll
        for (int q = 0; q < 4; ++q) {
            float4 e = e4[q * 64 + l];
            dot = fmaf(rx[q].x, e.x, dot);
            dot = fmaf(rx[q].y, e.y, dot);
            dot = fmaf(rx[q].z, e.z, dot);
            dot = fmaf(rx[q].w, e.w, dot);
        }
        #pragma unroll
        for (int m = 1; m < 64; m <<= 1) dot += __shfl_xor(dot, m);
        dots[c] = dot;             // uniform
    }

    // --- final selection (uniform computation on all lanes)
    const float rv = rr[b];
    float bv = FINF; int bi = IBIG;
    #pragma unroll
    for (int c = 0; c < NCAND; ++c) {
        const float s = (rv - 2.0f * dots[c]) + ee[cand[c]];
        amin(bv, bi, s, cand[c]);
    }
    if (l == 0) codes[(size_t)b * H_ + h] = (float)bi;

    // --- exact fp32 residual update (order matches reference elementwise)
    const float4* q4 = reinterpret_cast<const float4*>(E + (size_t)bi * D_);
    float4* r4w = reinterpret_cast<float4*>(resid + (size_t)b * D_);
    uchar4* h4w = reinterpret_cast<uchar4*>(r8 + (size_t)b * D_);
    float nrm = 0.f;
    #pragma unroll
    for (int q = 0; q < 4; ++q) {
        float4 qv = q4[q * 64 + l];
        float4 r = rx[q];
        r.x -= qv.x; r.y -= qv.y; r.z -= qv.z; r.w -= qv.w;
        rx[q] = r;
        r4w[q * 64 + l] = r;
        uchar4 hh;
        hh.x = f2e4m3(r.x); hh.y = f2e4m3(r.y);
        hh.z = f2e4m3(r.z); hh.w = f2e4m3(r.w);
        h4w[q * 64 + l] = hh;
        nrm += r.x * r.x + r.y * r.y + r.z * r.z + r.w * r.w;
    }
    #pragma unroll
    for (int m = 1; m < 64; m <<= 1) nrm += __shfl_xor(nrm, m);
    if (l == 0) rr[b] = nrm;

    // --- last head: quantized = x - resid_final (reconstruction err ~1e-5)
    if (h == H_ - 1) {
        const float4* x4 = reinterpret_cast<const float4*>(x + (size_t)b * D_);
        float4* o4 = reinterpret_cast<float4*>(quant + (size_t)b * D_);
        #pragma unroll
        for (int q = 0; q < 4; ++q) {
            float4 xv = x4[q * 64 + l];
            float4 o;
            o.x = xv.x - rx[q].x; o.y = xv.y - rx[q].y;
            o.z = xv.z - rx[q].z; o.w = xv.w - rx[q].w;
            o4[q * 64 + l] = o;
        }
    }
}

// ---------------------------------------------------------------------------
extern "C" void kernel_launch(void* const* d_in, const int* in_sizes, int n_in,
                              void* d_out, int out_size, void* d_ws, size_t ws_size,
                              hipStream_t stream) {
    const float* x  = (const float*)d_in[0];   // [B][1][D]
    const float* cb = (const float*)d_in[1];   // [H][K][D]
    float* out = (float*)d_out;
    float* quant = out;                          // [B][D]
    float* codes = out + (size_t)B_ * D_;        // [B][H] as float

    char* ws = (char*)d_ws;
    size_t off = 0;
    float* resid = (float*)(ws + off); off += (size_t)B_ * D_ * 4;              // 32 MB
    float* rr    = (float*)(ws + off); off += (size_t)B_ * 4;
    float* ee    = (float*)(ws + off); off += (size_t)H_ * K_ * 4;              // 128 KB
    float* pval  = (float*)(ws + off); off += (size_t)B_ * NBLK * TOPB * 4;     // 6.3 MB
    int*   pidx  = (int*)  (ws + off); off += (size_t)B_ * NBLK * TOPB * 4;     // 6.3 MB
    unsigned char* r8 = (unsigned char*)(ws + off); off += (size_t)B_ * D_;     // 8 MB
    unsigned char* c8 = (unsigned char*)(ws + off); off += (size_t)K_ * D_;     // 4 MB

    hipLaunchKernelGGL(init_kernel, dim3(B_), dim3(256), 0, stream, x, resid, rr, r8);

    for (int h = 0; h < H_; ++h) {
        const float* E  = cb + (size_t)h * K_ * D_;
        float* eh = ee + (size_t)h * K_;
        const float sH = (float)(1 << h);
        hipLaunchKernelGGL(cbconv_kernel, dim3(K_), dim3(256), 0, stream, E, c8, eh, sH);
        hipLaunchKernelGGL(score_mfma_kernel, dim3((K_ / BN) * (B_ / BM)), dim3(256),
                           0, stream, c8, r8, eh, sH, pval, pidx);
        hipLaunchKernelGGL(update_kernel, dim3(B_ / 4), dim3(256), 0, stream,
                           resid, E, eh, pval, pidx, rr, codes, r8, x, quant, h);
    }
}